// Round 4
// baseline (252.452 us; speedup 1.0000x reference)
//
#include <hip/hip_runtime.h>
#include <hip/hip_bf16.h>
#include <cstdint>
#include <cstddef>

// Problem constants (B=4, N=256, D=32, H=512)
#define NB 4
#define NN 256
#define DD 32
#define HH 512

typedef __attribute__((ext_vector_type(8))) short short8;    // 8 bf16 (4 VGPRs) — MFMA A/B frag
typedef __attribute__((ext_vector_type(4))) float f32x4;     // 16x16 C/D frag
typedef __attribute__((ext_vector_type(16))) float f32x16;   // 32x32 C/D frag

// HW packed fp32->bf16 (RNE). a -> low 16, b -> high 16.
static __device__ __forceinline__ unsigned cvtpk(float a, float b) {
  unsigned r;
  asm("v_cvt_pk_bf16_f32 %0, %1, %2" : "=v"(r) : "v"(a), "v"(b));
  return r;
}
static __device__ __forceinline__ unsigned short f2bf1(float a) {
  return (unsigned short)(cvtpk(a, 0.f) & 0xffffu);
}

// ---------------------------------------------------------------------------
// prep_all (grid 384x256): three regions by thread id.
//  A: t in [0,16384):     zbf (bf16 copy of z), 2 elems/thread
//  B: t in [16384,32768): W2F — W2 (512x256) in 32x32x16 MFMA B-frag order:
//       elem[(((w*8+hc)*4+s)*2+nt)*512 + lane*8 + e] = W2[h][k2]
//       h = hc*64+s*16+(lane>>5)*8+e ; k2 = w*64+nt*32+(lane&31)
//  C: t in [32768,98304): W1F — W1 in 16x16x32 B-frag order for prep_T2
// ---------------------------------------------------------------------------
__global__ __launch_bounds__(256) void prep_all(const float* __restrict__ z,
                                                const float* __restrict__ W1,
                                                const float* __restrict__ W2,
                                                unsigned short* __restrict__ zbf,
                                                unsigned short* __restrict__ W2F,
                                                unsigned short* __restrict__ W1F) {
  int t = blockIdx.x * 256 + threadIdx.x;
  if (t < 16384) {
    float2 v = ((const float2*)z)[t];
    ((unsigned*)zbf)[t] = cvtpk(v.x, v.y);
  } else if (t < 32768) {
    int f8 = t - 16384;                   // frag-slot index (8 elems each)
    int lane = f8 & 63;
    int nt = (f8 >> 6) & 1, s = (f8 >> 7) & 3, hc = (f8 >> 9) & 7, w = (f8 >> 12) & 3;
    int k2 = w * 64 + nt * 32 + (lane & 31);
    int hb = hc * 64 + s * 16 + (lane >> 5) * 8;
    float v[8];
    #pragma unroll
    for (int e = 0; e < 8; ++e) v[e] = W2[(hb + e) * 256 + k2];
    uint4 p;
    p.x = cvtpk(v[0], v[1]); p.y = cvtpk(v[2], v[3]);
    p.z = cvtpk(v[4], v[5]); p.w = cvtpk(v[6], v[7]);
    ((uint4*)W2F)[f8] = p;
  } else {
    int g = t - 32768;                    // [0, 65536)
    int n = ((g >> 6) << 4) | (g & 15);   // n = h*32 + c, the output column
    int quad = (g >> 4) & 3;
    int c = n & 31, h = n >> 5;
    float v[8];
    #pragma unroll
    for (int e = 0; e < 8; ++e) {
      int a = quad * 8 + e;
      v[e] = W1[(a * 32 + c) * 512 + h];
    }
    uint4 p;
    p.x = cvtpk(v[0], v[1]); p.y = cvtpk(v[2], v[3]);
    p.z = cvtpk(v[4], v[5]); p.w = cvtpk(v[6], v[7]);
    ((uint4*)W1F)[g] = p;
  }
}

// ---------------------------------------------------------------------------
// prep_T2: Tall[bi][n] = sum_a z[bi][a] * W1p[a][n]  as MFMA GEMM (16x16x32)
// ---------------------------------------------------------------------------
__global__ __launch_bounds__(256) void prep_T2(const unsigned short* __restrict__ zbf,
                                               const unsigned short* __restrict__ W1F,
                                               unsigned short* __restrict__ Tall) {
  const int tid = threadIdx.x;
  const int w = tid >> 6, lane = tid & 63;
  const int quad = lane >> 4, l16 = lane & 15;
  const int nblk = blockIdx.x, mblk = blockIdx.y;
  const int bibase = mblk * 64;

  short8 afr[4], bfr[4];
  #pragma unroll
  for (int mt = 0; mt < 4; ++mt)
    afr[mt] = *(const short8*)(zbf + (size_t)(bibase + mt * 16 + l16) * 32 + quad * 8);
  #pragma unroll
  for (int nt = 0; nt < 4; ++nt)
    bfr[nt] = *(const short8*)(W1F + (size_t)(nblk * 16 + w * 4 + nt) * 512 + lane * 8);

  f32x4 d[4][4];
  #pragma unroll
  for (int mt = 0; mt < 4; ++mt)
    #pragma unroll
    for (int nt = 0; nt < 4; ++nt)
      d[mt][nt] = __builtin_amdgcn_mfma_f32_16x16x32_bf16(
          afr[mt], bfr[nt], (f32x4){0.f, 0.f, 0.f, 0.f}, 0, 0, 0);

  const int ncol = nblk * 256 + w * 64;
  #pragma unroll
  for (int mt = 0; mt < 4; ++mt)
    #pragma unroll
    for (int r = 0; r < 4; ++r) {
      size_t rowoff = (size_t)(bibase + mt * 16 + quad * 4 + r) * 16384;
      #pragma unroll
      for (int nt = 0; nt < 4; ++nt)
        Tall[rowoff + ncol + nt * 16 + l16] = f2bf1(d[mt][nt][r]);
    }
}

// ---------------------------------------------------------------------------
// fused: block = (b,i,jt of 64 j), 4 waves; wave w owns k2 in [64w, 64w+64).
// NO barriers in the K-loop: each wave computes the full 64x64 h1 chunk
// itself (4x redundant phase-1 buys wave independence) using 32x32x16 MFMA.
// Phase-1 D (col=lane&31=j) is already on the correct lane for phase-2's
// A-operand (m=lane&31=j); only the h-halves swap between lane-half partners
// via one pre-selected shfl_xor(32) per uint-pair. Bias b1 rides in as the
// MFMA C-operand. One __syncthreads total (k-reduction epilogue).
// ---------------------------------------------------------------------------
__global__ __launch_bounds__(256) void fused(const unsigned short* __restrict__ Tall,
                                             const unsigned short* __restrict__ W2F,
                                             const unsigned short* __restrict__ zbf,
                                             const float* __restrict__ b1,
                                             const float* __restrict__ b2,
                                             const float* __restrict__ W3,
                                             const float* __restrict__ b3,
                                             const float* __restrict__ motif,
                                             float* __restrict__ out) {
  __shared__ float red[256];

  const int tid = threadIdx.x;
  const int w = tid >> 6, lane = tid & 63;
  const int L = lane >> 5, c32 = lane & 31;

  // XCD swizzle: 4 jt-siblings of one bi land on the same XCD (bx % 8 equal)
  const int bx = blockIdx.x;
  const int jt = (bx >> 3) & 3;
  const int bi = (bx & 7) | ((bx >> 5) << 3);   // b*256 + i
  const int b = bi >> 8, i = bi & 255;
  const int jbase = jt * 64;

  // hc-invariant z frags: B[k=c][n=j], n=lane&31=j_rel, k=(lane>>5)*8+e (+16*s2)
  short8 zfr[2][2];
  #pragma unroll
  for (int jt2 = 0; jt2 < 2; ++jt2)
    #pragma unroll
    for (int s2 = 0; s2 < 2; ++s2)
      zfr[jt2][s2] = *(const short8*)(zbf +
          (size_t)(b * 256 + jbase + jt2 * 32 + c32) * 32 + s2 * 16 + L * 8);

  // epilogue constants: this wave owns k2 in [64w, 64w+64)
  float b2v[2], w3v[2];
  #pragma unroll
  for (int nt = 0; nt < 2; ++nt) {
    int k2 = w * 64 + nt * 32 + c32;
    b2v[nt] = b2[k2];
    w3v[nt] = W3[k2];
  }

  f32x16 acc[2][2];
  #pragma unroll
  for (int mt = 0; mt < 2; ++mt)
    #pragma unroll
    for (int nt = 0; nt < 2; ++nt)
      acc[mt][nt] = (f32x16){0.f,0.f,0.f,0.f,0.f,0.f,0.f,0.f,
                             0.f,0.f,0.f,0.f,0.f,0.f,0.f,0.f};

  const unsigned short* tP = Tall + (size_t)bi * 16384 + c32 * 32 + L * 8;
  const unsigned short* wP = W2F + w * 32768 + lane * 8;
  const float* b1P = b1 + 4 * L;

  for (int hc = 0; hc < 8; ++hc) {
    #pragma unroll
    for (int ht = 0; ht < 2; ++ht) {
      // T A-frags: A[m=h_rel=lane&31][k=c], two k-steps of 16
      short8 t0 = *(const short8*)(tP + ht * 1024);
      short8 t1 = *(const short8*)(tP + ht * 1024 + 16);
      // bias as MFMA C-init: D reg 4g+r <-> h_rel = r + 8g + 4L
      float4 b1f[4];
      #pragma unroll
      for (int g = 0; g < 4; ++g)
        b1f[g] = *(const float4*)(b1P + ht * 32 + g * 8);
      f32x16 dinit;
      #pragma unroll
      for (int g = 0; g < 4; ++g) {
        dinit[g * 4 + 0] = b1f[g].x; dinit[g * 4 + 1] = b1f[g].y;
        dinit[g * 4 + 2] = b1f[g].z; dinit[g * 4 + 3] = b1f[g].w;
      }
      // phase 1: h1[h 32][j 64] for this ht, relu+pack to bf16 pairs
      unsigned pk[2][8];   // [jt2][g*2+p], pk[g*2+p] = (h_rel 8g+4L+2p, +1)
      #pragma unroll
      for (int jt2 = 0; jt2 < 2; ++jt2) {
        f32x16 d = __builtin_amdgcn_mfma_f32_32x32x16_bf16(t0, zfr[jt2][0], dinit, 0, 0, 0);
        d = __builtin_amdgcn_mfma_f32_32x32x16_bf16(t1, zfr[jt2][1], d, 0, 0, 0);
        #pragma unroll
        for (int g = 0; g < 4; ++g)
          #pragma unroll
          for (int p = 0; p < 2; ++p) {
            float v0 = fmaxf(d[g * 4 + p * 2 + 0], 0.f);
            float v1 = fmaxf(d[g * 4 + p * 2 + 1], 0.f);
            pk[jt2][g * 2 + p] = cvtpk(v0, v1);
          }
      }
      // phase 2: two k-steps (s = 2*ht + sh) of 16 h each
      #pragma unroll
      for (int sh = 0; sh < 2; ++sh) {
        const int s = ht * 2 + sh;
        short8 bf0 = *(const short8*)(wP + (s * 2 + 0) * 512);
        short8 bf1 = *(const short8*)(wP + (s * 2 + 1) * 512);
        #pragma unroll
        for (int mt = 0; mt < 2; ++mt) {
          // A-frag assembly: lane needs h = 16s + 8L + e; own regs cover
          // e in [4L,4L+4), partner (lane^32) covers the rest.
          unsigned plo0 = pk[mt][sh * 4 + 0], plo1 = pk[mt][sh * 4 + 1];
          unsigned phi0 = pk[mt][sh * 4 + 2], phi1 = pk[mt][sh * 4 + 3];
          unsigned tmp0 = L ? plo0 : phi0;          // what partner needs
          unsigned tmp1 = L ? plo1 : phi1;
          unsigned x0 = __shfl_xor(tmp0, 32);
          unsigned x1 = __shfl_xor(tmp1, 32);
          union { unsigned u[4]; short8 s8; } af;
          af.u[0] = L ? x0 : plo0;
          af.u[1] = L ? x1 : plo1;
          af.u[2] = L ? phi0 : x0;
          af.u[3] = L ? phi1 : x1;
          acc[mt][0] = __builtin_amdgcn_mfma_f32_32x32x16_bf16(af.s8, bf0, acc[mt][0], 0, 0, 0);
          acc[mt][1] = __builtin_amdgcn_mfma_f32_32x32x16_bf16(af.s8, bf1, acc[mt][1], 0, 0, 0);
        }
      }
    }
    tP += 2048;   // next 64-h chunk of Tall row
    wP += 4096;   // next hc block of W2F
    b1P += 64;
  }

  // ---- epilogue: relu(h2+b2) . W3, reduce over k2 (32 lanes), then 4 waves
  float pr[2][16];
  #pragma unroll
  for (int mt = 0; mt < 2; ++mt)
    #pragma unroll
    for (int reg = 0; reg < 16; ++reg) {
      float s = 0.f;
      #pragma unroll
      for (int nt = 0; nt < 2; ++nt) {
        float v = acc[mt][nt][reg] + b2v[nt];
        v = v > 0.f ? v : 0.f;
        s += v * w3v[nt];
      }
      s += __shfl_xor(s, 1);
      s += __shfl_xor(s, 2);
      s += __shfl_xor(s, 4);
      s += __shfl_xor(s, 8);
      s += __shfl_xor(s, 16);
      pr[mt][reg] = s;
    }
  if (c32 == 0) {
    #pragma unroll
    for (int mt = 0; mt < 2; ++mt)
      #pragma unroll
      for (int g = 0; g < 4; ++g) {
        float4 vv = {pr[mt][g * 4 + 0], pr[mt][g * 4 + 1],
                     pr[mt][g * 4 + 2], pr[mt][g * 4 + 3]};
        // j_rel = mt*32 + 8g + 4L + r
        *(float4*)&red[w * 64 + mt * 32 + g * 8 + L * 4] = vv;
      }
  }
  __syncthreads();
  if (tid < 64) {
    int j = tid;
    float logit = red[j] + red[64 + j] + red[128 + j] + red[192 + j] + b3[0];
    float mm = motif[b * 256 + i] * motif[b * 256 + jbase + j];
    logit *= mm;
    float map = 1.f / (1.f + expf(-logit));
    size_t idx = (size_t)(b * 256 + i) * 256 + jbase + j;
    out[idx] = map;                           // contact_map
    out[(size_t)NB * NN * NN + idx] = logit;  // contact_logits
  }
}

// ---------------------------------------------------------------------------
extern "C" void kernel_launch(void* const* d_in, const int* in_sizes, int n_in,
                              void* d_out, int out_size, void* d_ws, size_t ws_size,
                              hipStream_t stream) {
  const float* z     = (const float*)d_in[0];
  const float* motif = (const float*)d_in[1];
  // d_in[2] residue_mask: all-ones, unused by the reference computation
  const float* W1 = (const float*)d_in[3];
  const float* b1 = (const float*)d_in[4];
  const float* W2 = (const float*)d_in[5];
  const float* b2 = (const float*)d_in[6];
  const float* W3 = (const float*)d_in[7];
  const float* b3 = (const float*)d_in[8];
  float* out = (float*)d_out;

  char* ws = (char*)d_ws;
  unsigned short* Tall = (unsigned short*)ws;                       // 32 MiB
  unsigned short* W2F  = (unsigned short*)(ws + 33554432);          // 256 KiB
  unsigned short* zbf  = (unsigned short*)(ws + 33554432 + 262144); // 64 KiB
  unsigned short* W1F  = (unsigned short*)(ws + 33554432 + 262144 + 65536); // 1 MiB

  prep_all<<<384, 256, 0, stream>>>(z, W1, W2, zbf, W2F, W1F);
  prep_T2<<<dim3(64, 16), 256, 0, stream>>>(zbf, W1F, Tall);
  fused<<<4096, 256, 0, stream>>>(Tall, W2F, zbf, b1, b2, W3, b3, motif, out);
}

// Round 5
// 185.036 us; speedup vs baseline: 1.3643x; 1.3643x over previous
//
#include <hip/hip_runtime.h>
#include <hip/hip_bf16.h>
#include <cstdint>
#include <cstddef>

// Problem constants (B=4, N=256, D=32, H=512)
#define NB 4
#define NN 256
#define DD 32
#define HH 512

typedef __attribute__((ext_vector_type(8))) short short8;    // 8 bf16 (4 VGPRs) — MFMA A/B frag
typedef __attribute__((ext_vector_type(4))) float f32x4;     // 16x16 C/D frag
typedef __attribute__((ext_vector_type(16))) float f32x16;   // 32x32 C/D frag

// HW packed fp32->bf16 (RNE). a -> low 16, b -> high 16.
static __device__ __forceinline__ unsigned cvtpk(float a, float b) {
  unsigned r;
  asm("v_cvt_pk_bf16_f32 %0, %1, %2" : "=v"(r) : "v"(a), "v"(b));
  return r;
}
static __device__ __forceinline__ unsigned short f2bf1(float a) {
  return (unsigned short)(cvtpk(a, 0.f) & 0xffffu);
}

// ---------------------------------------------------------------------------
// prep_all (grid 384x256): three regions by thread id.
//  A: t in [0,16384):     zbf (bf16 copy of z), 2 elems/thread
//  B: t in [16384,32768): W2F — W2 (512x256) in 32x32x16 MFMA B-frag order:
//       elem[(((w*8+hc)*4+s)*2+nt)*512 + lane*8 + e] = W2[h][k2]
//       h = hc*64+s*16+(lane>>5)*8+e ; k2 = w*64+nt*32+(lane&31)
//  C: t in [32768,98304): W1F — W1 in 16x16x32 B-frag order for prep_T2
// ---------------------------------------------------------------------------
__global__ __launch_bounds__(256) void prep_all(const float* __restrict__ z,
                                                const float* __restrict__ W1,
                                                const float* __restrict__ W2,
                                                unsigned short* __restrict__ zbf,
                                                unsigned short* __restrict__ W2F,
                                                unsigned short* __restrict__ W1F) {
  int t = blockIdx.x * 256 + threadIdx.x;
  if (t < 16384) {
    float2 v = ((const float2*)z)[t];
    ((unsigned*)zbf)[t] = cvtpk(v.x, v.y);
  } else if (t < 32768) {
    int f8 = t - 16384;                   // frag-slot index (8 elems each)
    int lane = f8 & 63;
    int nt = (f8 >> 6) & 1, s = (f8 >> 7) & 3, hc = (f8 >> 9) & 7, w = (f8 >> 12) & 3;
    int k2 = w * 64 + nt * 32 + (lane & 31);
    int hb = hc * 64 + s * 16 + (lane >> 5) * 8;
    float v[8];
    #pragma unroll
    for (int e = 0; e < 8; ++e) v[e] = W2[(hb + e) * 256 + k2];
    uint4 p;
    p.x = cvtpk(v[0], v[1]); p.y = cvtpk(v[2], v[3]);
    p.z = cvtpk(v[4], v[5]); p.w = cvtpk(v[6], v[7]);
    ((uint4*)W2F)[f8] = p;
  } else {
    int g = t - 32768;                    // [0, 65536)
    int n = ((g >> 6) << 4) | (g & 15);   // n = h*32 + c, the output column
    int quad = (g >> 4) & 3;
    int c = n & 31, h = n >> 5;
    float v[8];
    #pragma unroll
    for (int e = 0; e < 8; ++e) {
      int a = quad * 8 + e;
      v[e] = W1[(a * 32 + c) * 512 + h];
    }
    uint4 p;
    p.x = cvtpk(v[0], v[1]); p.y = cvtpk(v[2], v[3]);
    p.z = cvtpk(v[4], v[5]); p.w = cvtpk(v[6], v[7]);
    ((uint4*)W1F)[g] = p;
  }
}

// ---------------------------------------------------------------------------
// prep_T2: Tall[bi][n] = sum_a z[bi][a] * W1p[a][n]  as MFMA GEMM (16x16x32)
// ---------------------------------------------------------------------------
__global__ __launch_bounds__(256) void prep_T2(const unsigned short* __restrict__ zbf,
                                               const unsigned short* __restrict__ W1F,
                                               unsigned short* __restrict__ Tall) {
  const int tid = threadIdx.x;
  const int w = tid >> 6, lane = tid & 63;
  const int quad = lane >> 4, l16 = lane & 15;
  const int nblk = blockIdx.x, mblk = blockIdx.y;
  const int bibase = mblk * 64;

  short8 afr[4], bfr[4];
  #pragma unroll
  for (int mt = 0; mt < 4; ++mt)
    afr[mt] = *(const short8*)(zbf + (size_t)(bibase + mt * 16 + l16) * 32 + quad * 8);
  #pragma unroll
  for (int nt = 0; nt < 4; ++nt)
    bfr[nt] = *(const short8*)(W1F + (size_t)(nblk * 16 + w * 4 + nt) * 512 + lane * 8);

  f32x4 d[4][4];
  #pragma unroll
  for (int mt = 0; mt < 4; ++mt)
    #pragma unroll
    for (int nt = 0; nt < 4; ++nt)
      d[mt][nt] = __builtin_amdgcn_mfma_f32_16x16x32_bf16(
          afr[mt], bfr[nt], (f32x4){0.f, 0.f, 0.f, 0.f}, 0, 0, 0);

  const int ncol = nblk * 256 + w * 64;
  #pragma unroll
  for (int mt = 0; mt < 4; ++mt)
    #pragma unroll
    for (int r = 0; r < 4; ++r) {
      size_t rowoff = (size_t)(bibase + mt * 16 + quad * 4 + r) * 16384;
      #pragma unroll
      for (int nt = 0; nt < 4; ++nt)
        Tall[rowoff + ncol + nt * 16 + l16] = f2bf1(d[mt][nt][r]);
    }
}

// ---------------------------------------------------------------------------
// fused: block = (b,i,jt of 64 j), 4 waves. R3 skeleton (shared phase-1 via
// double-buffered LDS, 1 barrier/hc) + verified 32x32x16 phase-2 + b1-as-C +
// fully unrolled hc loop + XCD swizzle.
//   phase1 (16x16x32): wave w computes h rows [w*16,+16) x 64 j into h1s.
//   phase2 (32x32x16): wave w owns k2 [64w,+64): acc[2mt][2nt] f32x16,
//     A-frag = h1s[j=c32][h=s*16+L*8..], conflict-free b128 (stride 72 sh).
// ---------------------------------------------------------------------------
__global__ __launch_bounds__(256) void fused(const unsigned short* __restrict__ Tall,
                                             const unsigned short* __restrict__ W2F,
                                             const unsigned short* __restrict__ zbf,
                                             const float* __restrict__ b1,
                                             const float* __restrict__ b2,
                                             const float* __restrict__ W3,
                                             const float* __restrict__ b3,
                                             const float* __restrict__ motif,
                                             float* __restrict__ out) {
  __shared__ unsigned short h1s[2][64 * 72];   // [j][h], pad 72
  __shared__ float red[256];

  const int tid = threadIdx.x;
  const int w = tid >> 6, lane = tid & 63;
  const int quad = lane >> 4, l16 = lane & 15;
  const int L = lane >> 5, c32 = lane & 31;

  // XCD swizzle: 4 jt-siblings of one bi land on the same XCD (bx % 8 equal)
  const int bx = blockIdx.x;
  const int jt = (bx >> 3) & 3;
  const int bi = (bx & 7) | ((bx >> 5) << 3);   // b*256 + i
  const int b = bi >> 8, i = bi & 255;
  const int jbase = jt * 64;

  // phase-1 z frags (16x16x32 B-operand): [k=c=quad*8+e][n=j=l16]
  short8 zfr[4];
  #pragma unroll
  for (int nt = 0; nt < 4; ++nt)
    zfr[nt] = *(const short8*)(zbf + (size_t)(b * 256 + jbase + nt * 16 + l16) * 32 + quad * 8);

  // epilogue constants: this wave owns k2 in [64w, 64w+64)
  float b2v[2], w3v[2];
  #pragma unroll
  for (int nt = 0; nt < 2; ++nt) {
    int k2 = w * 64 + nt * 32 + c32;
    b2v[nt] = b2[k2];
    w3v[nt] = W3[k2];
  }

  f32x16 acc[2][2];
  #pragma unroll
  for (int mt = 0; mt < 2; ++mt)
    #pragma unroll
    for (int nt = 0; nt < 2; ++nt)
      acc[mt][nt] = (f32x16){0.f,0.f,0.f,0.f,0.f,0.f,0.f,0.f,
                             0.f,0.f,0.f,0.f,0.f,0.f,0.f,0.f};

  const unsigned short* Tbase = Tall + (size_t)bi * 16384 + (w * 16 + l16) * 32 + quad * 8;
  const unsigned short* Wp = W2F + w * 32768 + lane * 8;
  const float* b1base = b1 + w * 16 + quad * 4;

  // phase1(hc): h1 rows [w*16,+16) x 64 j -> h1s[buf], b1 rides as C-operand
  auto phase1 = [&](int hc, int buf) {
    short8 tfr = *(const short8*)(Tbase + hc * 2048);
    float4 b1f = *(const float4*)(b1base + hc * 64);
    f32x4 cin = {b1f.x, b1f.y, b1f.z, b1f.w};
    #pragma unroll
    for (int nt = 0; nt < 4; ++nt) {
      f32x4 d = __builtin_amdgcn_mfma_f32_16x16x32_bf16(tfr, zfr[nt], cin, 0, 0, 0);
      // D: row = quad*4+r -> h_rel, col = l16 -> j within nt's 16
      uint2 p;
      p.x = cvtpk(fmaxf(d[0], 0.f), fmaxf(d[1], 0.f));
      p.y = cvtpk(fmaxf(d[2], 0.f), fmaxf(d[3], 0.f));
      *(uint2*)&h1s[buf][(nt * 16 + l16) * 72 + w * 16 + quad * 4] = p;
    }
  };

  phase1(0, 0);
  __syncthreads();

  #pragma unroll
  for (int hc = 0; hc < 8; ++hc) {
    const int buf = hc & 1;
    #pragma unroll
    for (int s = 0; s < 4; ++s) {        // 4 k-steps of 16 h
      short8 bf0 = *(const short8*)(Wp + ((hc * 4 + s) * 2 + 0) * 512);
      short8 bf1 = *(const short8*)(Wp + ((hc * 4 + s) * 2 + 1) * 512);
      short8 af0 = *(const short8*)&h1s[buf][(c32) * 72 + s * 16 + L * 8];
      short8 af1 = *(const short8*)&h1s[buf][(32 + c32) * 72 + s * 16 + L * 8];
      acc[0][0] = __builtin_amdgcn_mfma_f32_32x32x16_bf16(af0, bf0, acc[0][0], 0, 0, 0);
      acc[0][1] = __builtin_amdgcn_mfma_f32_32x32x16_bf16(af0, bf1, acc[0][1], 0, 0, 0);
      acc[1][0] = __builtin_amdgcn_mfma_f32_32x32x16_bf16(af1, bf0, acc[1][0], 0, 0, 0);
      acc[1][1] = __builtin_amdgcn_mfma_f32_32x32x16_bf16(af1, bf1, acc[1][1], 0, 0, 0);
    }
    if (hc < 7) phase1(hc + 1, buf ^ 1);
    __syncthreads();
  }

  // ---- epilogue: relu(h2+b2) . W3, reduce over k2 (32 lanes), then 4 waves
  float pr[2][16];
  #pragma unroll
  for (int mt = 0; mt < 2; ++mt)
    #pragma unroll
    for (int reg = 0; reg < 16; ++reg) {
      float s = 0.f;
      #pragma unroll
      for (int nt = 0; nt < 2; ++nt) {
        float v = acc[mt][nt][reg] + b2v[nt];
        v = v > 0.f ? v : 0.f;
        s += v * w3v[nt];
      }
      s += __shfl_xor(s, 1);
      s += __shfl_xor(s, 2);
      s += __shfl_xor(s, 4);
      s += __shfl_xor(s, 8);
      s += __shfl_xor(s, 16);
      pr[mt][reg] = s;
    }
  if (c32 == 0) {
    #pragma unroll
    for (int mt = 0; mt < 2; ++mt)
      #pragma unroll
      for (int g = 0; g < 4; ++g) {
        float4 vv = {pr[mt][g * 4 + 0], pr[mt][g * 4 + 1],
                     pr[mt][g * 4 + 2], pr[mt][g * 4 + 3]};
        // j_rel = mt*32 + 8g + 4L + r
        *(float4*)&red[w * 64 + mt * 32 + g * 8 + L * 4] = vv;
      }
  }
  __syncthreads();
  if (tid < 64) {
    int j = tid;
    float logit = red[j] + red[64 + j] + red[128 + j] + red[192 + j] + b3[0];
    float mm = motif[b * 256 + i] * motif[b * 256 + jbase + j];
    logit *= mm;
    float map = 1.f / (1.f + expf(-logit));
    size_t idx = (size_t)(b * 256 + i) * 256 + jbase + j;
    out[idx] = map;                           // contact_map
    out[(size_t)NB * NN * NN + idx] = logit;  // contact_logits
  }
}

// ---------------------------------------------------------------------------
extern "C" void kernel_launch(void* const* d_in, const int* in_sizes, int n_in,
                              void* d_out, int out_size, void* d_ws, size_t ws_size,
                              hipStream_t stream) {
  const float* z     = (const float*)d_in[0];
  const float* motif = (const float*)d_in[1];
  // d_in[2] residue_mask: all-ones, unused by the reference computation
  const float* W1 = (const float*)d_in[3];
  const float* b1 = (const float*)d_in[4];
  const float* W2 = (const float*)d_in[5];
  const float* b2 = (const float*)d_in[6];
  const float* W3 = (const float*)d_in[7];
  const float* b3 = (const float*)d_in[8];
  float* out = (float*)d_out;

  char* ws = (char*)d_ws;
  unsigned short* Tall = (unsigned short*)ws;                       // 32 MiB
  unsigned short* W2F  = (unsigned short*)(ws + 33554432);          // 256 KiB
  unsigned short* zbf  = (unsigned short*)(ws + 33554432 + 262144); // 64 KiB
  unsigned short* W1F  = (unsigned short*)(ws + 33554432 + 262144 + 65536); // 1 MiB

  prep_all<<<384, 256, 0, stream>>>(z, W1, W2, zbf, W2F, W1F);
  prep_T2<<<dim3(64, 16), 256, 0, stream>>>(zbf, W1F, Tall);
  fused<<<4096, 256, 0, stream>>>(Tall, W2F, zbf, b1, b2, W3, b3, motif, out);
}

// Round 6
// 184.524 us; speedup vs baseline: 1.3681x; 1.0028x over previous
//
#include <hip/hip_runtime.h>
#include <hip/hip_bf16.h>
#include <cstdint>
#include <cstddef>

// Problem constants (B=4, N=256, D=32, H=512)
#define NB 4
#define NN 256
#define DD 32
#define HH 512

typedef __attribute__((ext_vector_type(8))) short short8;    // 8 bf16 (4 VGPRs) — MFMA A/B frag
typedef __attribute__((ext_vector_type(4))) float f32x4;     // 16x16 C/D frag
typedef __attribute__((ext_vector_type(16))) float f32x16;   // 32x32 C/D frag

// HW packed fp32->bf16 (RNE). a -> low 16, b -> high 16.
static __device__ __forceinline__ unsigned cvtpk(float a, float b) {
  unsigned r;
  asm("v_cvt_pk_bf16_f32 %0, %1, %2" : "=v"(r) : "v"(a), "v"(b));
  return r;
}
static __device__ __forceinline__ unsigned short f2bf1(float a) {
  return (unsigned short)(cvtpk(a, 0.f) & 0xffffu);
}

// ---------------------------------------------------------------------------
// prep_all (grid 384x256): three regions by thread id.
//  A: t in [0,16384):     zbf (bf16 copy of z), 2 elems/thread
//  B: t in [16384,32768): W2F — W2 (512x256) in 32x32x16 MFMA B-frag order:
//       elem[(((w*8+hc)*4+s)*2+nt)*512 + lane*8 + e] = W2[h][k2]
//       h = hc*64+s*16+(lane>>5)*8+e ; k2 = w*64+nt*32+(lane&31)
//  C: t in [32768,98304): W1F — W1 in 16x16x32 B-frag order for prep_T2
// ---------------------------------------------------------------------------
__global__ __launch_bounds__(256) void prep_all(const float* __restrict__ z,
                                                const float* __restrict__ W1,
                                                const float* __restrict__ W2,
                                                unsigned short* __restrict__ zbf,
                                                unsigned short* __restrict__ W2F,
                                                unsigned short* __restrict__ W1F) {
  int t = blockIdx.x * 256 + threadIdx.x;
  if (t < 16384) {
    float2 v = ((const float2*)z)[t];
    ((unsigned*)zbf)[t] = cvtpk(v.x, v.y);
  } else if (t < 32768) {
    int f8 = t - 16384;                   // frag-slot index (8 elems each)
    int lane = f8 & 63;
    int nt = (f8 >> 6) & 1, s = (f8 >> 7) & 3, hc = (f8 >> 9) & 7, w = (f8 >> 12) & 3;
    int k2 = w * 64 + nt * 32 + (lane & 31);
    int hb = hc * 64 + s * 16 + (lane >> 5) * 8;
    float v[8];
    #pragma unroll
    for (int e = 0; e < 8; ++e) v[e] = W2[(hb + e) * 256 + k2];
    uint4 p;
    p.x = cvtpk(v[0], v[1]); p.y = cvtpk(v[2], v[3]);
    p.z = cvtpk(v[4], v[5]); p.w = cvtpk(v[6], v[7]);
    ((uint4*)W2F)[f8] = p;
  } else {
    int g = t - 32768;                    // [0, 65536)
    int n = ((g >> 6) << 4) | (g & 15);   // n = h*32 + c, the output column
    int quad = (g >> 4) & 3;
    int c = n & 31, h = n >> 5;
    float v[8];
    #pragma unroll
    for (int e = 0; e < 8; ++e) {
      int a = quad * 8 + e;
      v[e] = W1[(a * 32 + c) * 512 + h];
    }
    uint4 p;
    p.x = cvtpk(v[0], v[1]); p.y = cvtpk(v[2], v[3]);
    p.z = cvtpk(v[4], v[5]); p.w = cvtpk(v[6], v[7]);
    ((uint4*)W1F)[g] = p;
  }
}

// ---------------------------------------------------------------------------
// prep_T2: Tall[bi][n] = sum_a z[bi][a] * W1p[a][n]  as MFMA GEMM (16x16x32)
// ---------------------------------------------------------------------------
__global__ __launch_bounds__(256) void prep_T2(const unsigned short* __restrict__ zbf,
                                               const unsigned short* __restrict__ W1F,
                                               unsigned short* __restrict__ Tall) {
  const int tid = threadIdx.x;
  const int w = tid >> 6, lane = tid & 63;
  const int quad = lane >> 4, l16 = lane & 15;
  const int nblk = blockIdx.x, mblk = blockIdx.y;
  const int bibase = mblk * 64;

  short8 afr[4], bfr[4];
  #pragma unroll
  for (int mt = 0; mt < 4; ++mt)
    afr[mt] = *(const short8*)(zbf + (size_t)(bibase + mt * 16 + l16) * 32 + quad * 8);
  #pragma unroll
  for (int nt = 0; nt < 4; ++nt)
    bfr[nt] = *(const short8*)(W1F + (size_t)(nblk * 16 + w * 4 + nt) * 512 + lane * 8);

  f32x4 d[4][4];
  #pragma unroll
  for (int mt = 0; mt < 4; ++mt)
    #pragma unroll
    for (int nt = 0; nt < 4; ++nt)
      d[mt][nt] = __builtin_amdgcn_mfma_f32_16x16x32_bf16(
          afr[mt], bfr[nt], (f32x4){0.f, 0.f, 0.f, 0.f}, 0, 0, 0);

  const int ncol = nblk * 256 + w * 64;
  #pragma unroll
  for (int mt = 0; mt < 4; ++mt)
    #pragma unroll
    for (int r = 0; r < 4; ++r) {
      size_t rowoff = (size_t)(bibase + mt * 16 + quad * 4 + r) * 16384;
      #pragma unroll
      for (int nt = 0; nt < 4; ++nt)
        Tall[rowoff + ncol + nt * 16 + l16] = f2bf1(d[mt][nt][r]);
    }
}

// ---------------------------------------------------------------------------
// fused: block = (b,i,jt of 64 j), 4 waves. H split into 2 halves of 256:
//   per half: phase1 fills h1s[64j][256h] (16 MFMA/wave, 16x16x32, b1 as C)
//             -> barrier -> phase2 streams 64 unbroken 32x32x16 MFMAs
//             (16 u-steps, 1-deep pipelined frag loads) -> barrier.
// 4 barriers/block total (vs 8 in the per-hc version); LDS single-buffer
// 33.8 KB -> ~3 blocks/CU. Frag loads (W2F/Tall) are per-lane 16B global,
// L2-resident; LDS strides chosen so b64 writes / b128 reads sit at the
// bank floor (stride 264 shorts = 132 words ≡ 4 mod 32).
// ---------------------------------------------------------------------------
__global__ __launch_bounds__(256) void fused(const unsigned short* __restrict__ Tall,
                                             const unsigned short* __restrict__ W2F,
                                             const unsigned short* __restrict__ zbf,
                                             const float* __restrict__ b1,
                                             const float* __restrict__ b2,
                                             const float* __restrict__ W3,
                                             const float* __restrict__ b3,
                                             const float* __restrict__ motif,
                                             float* __restrict__ out) {
  __shared__ unsigned short h1s[64 * 264];   // [j][h_local], stride 264
  __shared__ float red[256];

  const int tid = threadIdx.x;
  const int w = tid >> 6, lane = tid & 63;
  const int quad = lane >> 4, l16 = lane & 15;
  const int L = lane >> 5, c32 = lane & 31;

  // XCD swizzle: 4 jt-siblings of one bi land on the same XCD (bx % 8 equal)
  const int bx = blockIdx.x;
  const int jt = (bx >> 3) & 3;
  const int bi = (bx & 7) | ((bx >> 5) << 3);   // b*256 + i
  const int b = bi >> 8, i = bi & 255;
  const int jbase = jt * 64;

  // phase-1 z frags (16x16x32 B-operand): [k=c=quad*8+e][n=j=l16]
  short8 zfr[4];
  #pragma unroll
  for (int nt = 0; nt < 4; ++nt)
    zfr[nt] = *(const short8*)(zbf + (size_t)(b * 256 + jbase + nt * 16 + l16) * 32 + quad * 8);

  // epilogue constants: this wave owns k2 in [64w, 64w+64)
  float b2v[2], w3v[2];
  #pragma unroll
  for (int nt = 0; nt < 2; ++nt) {
    int k2 = w * 64 + nt * 32 + c32;
    b2v[nt] = b2[k2];
    w3v[nt] = W3[k2];
  }

  f32x16 acc[2][2];
  #pragma unroll
  for (int mt = 0; mt < 2; ++mt)
    #pragma unroll
    for (int nt = 0; nt < 2; ++nt)
      acc[mt][nt] = (f32x16){0.f,0.f,0.f,0.f,0.f,0.f,0.f,0.f,
                             0.f,0.f,0.f,0.f,0.f,0.f,0.f,0.f};

  const unsigned short* Tbase = Tall + (size_t)bi * 16384 + (w * 16 + l16) * 32 + quad * 8;
  const unsigned short* Wp = W2F + w * 32768 + lane * 8;
  const float* b1base = b1 + w * 16 + quad * 4;

  #pragma unroll
  for (int half = 0; half < 2; ++half) {
    // ---- phase 1: h rows [w*16,+16) of 4 chunks x 64 j -> h1s
    short8 tfr[4];
    #pragma unroll
    for (int q = 0; q < 4; ++q)
      tfr[q] = *(const short8*)(Tbase + (half * 4 + q) * 2048);
    #pragma unroll
    for (int q = 0; q < 4; ++q) {
      float4 b1f = *(const float4*)(b1base + (half * 4 + q) * 64);
      f32x4 cin = {b1f.x, b1f.y, b1f.z, b1f.w};
      #pragma unroll
      for (int nt = 0; nt < 4; ++nt) {
        f32x4 d = __builtin_amdgcn_mfma_f32_16x16x32_bf16(tfr[q], zfr[nt], cin, 0, 0, 0);
        // D: row = quad*4+r -> h_rel, col = l16 -> j within nt's 16
        uint2 p;
        p.x = cvtpk(fmaxf(d[0], 0.f), fmaxf(d[1], 0.f));
        p.y = cvtpk(fmaxf(d[2], 0.f), fmaxf(d[3], 0.f));
        *(uint2*)&h1s[(nt * 16 + l16) * 264 + q * 64 + w * 16 + quad * 4] = p;
      }
    }
    __syncthreads();

    // ---- phase 2: 16 u-steps (h_local = u*16 + L*8), 1-deep pipelined
    const unsigned short* Wh = Wp + half * 16384;
    short8 bfA[2][2], afA[2][2];
    bfA[0][0] = *(const short8*)(Wh);
    bfA[0][1] = *(const short8*)(Wh + 512);
    afA[0][0] = *(const short8*)&h1s[c32 * 264 + L * 8];
    afA[0][1] = *(const short8*)&h1s[(32 + c32) * 264 + L * 8];
    #pragma unroll
    for (int u = 0; u < 16; ++u) {
      const int cur = u & 1, nxt = cur ^ 1;
      if (u < 15) {
        bfA[nxt][0] = *(const short8*)(Wh + (u + 1) * 1024);
        bfA[nxt][1] = *(const short8*)(Wh + (u + 1) * 1024 + 512);
        afA[nxt][0] = *(const short8*)&h1s[c32 * 264 + (u + 1) * 16 + L * 8];
        afA[nxt][1] = *(const short8*)&h1s[(32 + c32) * 264 + (u + 1) * 16 + L * 8];
      }
      acc[0][0] = __builtin_amdgcn_mfma_f32_32x32x16_bf16(afA[cur][0], bfA[cur][0], acc[0][0], 0, 0, 0);
      acc[0][1] = __builtin_amdgcn_mfma_f32_32x32x16_bf16(afA[cur][0], bfA[cur][1], acc[0][1], 0, 0, 0);
      acc[1][0] = __builtin_amdgcn_mfma_f32_32x32x16_bf16(afA[cur][1], bfA[cur][0], acc[1][0], 0, 0, 0);
      acc[1][1] = __builtin_amdgcn_mfma_f32_32x32x16_bf16(afA[cur][1], bfA[cur][1], acc[1][1], 0, 0, 0);
    }
    if (half == 0) __syncthreads();   // protect h1s before half-1 overwrites
  }

  // ---- epilogue: relu(h2+b2) . W3, reduce over k2 (32 lanes), then 4 waves
  float pr[2][16];
  #pragma unroll
  for (int mt = 0; mt < 2; ++mt)
    #pragma unroll
    for (int reg = 0; reg < 16; ++reg) {
      float s = 0.f;
      #pragma unroll
      for (int nt = 0; nt < 2; ++nt) {
        float v = acc[mt][nt][reg] + b2v[nt];
        v = v > 0.f ? v : 0.f;
        s += v * w3v[nt];
      }
      s += __shfl_xor(s, 1);
      s += __shfl_xor(s, 2);
      s += __shfl_xor(s, 4);
      s += __shfl_xor(s, 8);
      s += __shfl_xor(s, 16);
      pr[mt][reg] = s;
    }
  if (c32 == 0) {
    #pragma unroll
    for (int mt = 0; mt < 2; ++mt)
      #pragma unroll
      for (int g = 0; g < 4; ++g) {
        float4 vv = {pr[mt][g * 4 + 0], pr[mt][g * 4 + 1],
                     pr[mt][g * 4 + 2], pr[mt][g * 4 + 3]};
        // j_rel = mt*32 + 8g + 4L + r
        *(float4*)&red[w * 64 + mt * 32 + g * 8 + L * 4] = vv;
      }
  }
  __syncthreads();
  if (tid < 64) {
    int j = tid;
    float logit = red[j] + red[64 + j] + red[128 + j] + red[192 + j] + b3[0];
    float mm = motif[b * 256 + i] * motif[b * 256 + jbase + j];
    logit *= mm;
    float map = 1.f / (1.f + expf(-logit));
    size_t idx = (size_t)(b * 256 + i) * 256 + jbase + j;
    out[idx] = map;                           // contact_map
    out[(size_t)NB * NN * NN + idx] = logit;  // contact_logits
  }
}

// ---------------------------------------------------------------------------
extern "C" void kernel_launch(void* const* d_in, const int* in_sizes, int n_in,
                              void* d_out, int out_size, void* d_ws, size_t ws_size,
                              hipStream_t stream) {
  const float* z     = (const float*)d_in[0];
  const float* motif = (const float*)d_in[1];
  // d_in[2] residue_mask: all-ones, unused by the reference computation
  const float* W1 = (const float*)d_in[3];
  const float* b1 = (const float*)d_in[4];
  const float* W2 = (const float*)d_in[5];
  const float* b2 = (const float*)d_in[6];
  const float* W3 = (const float*)d_in[7];
  const float* b3 = (const float*)d_in[8];
  float* out = (float*)d_out;

  char* ws = (char*)d_ws;
  unsigned short* Tall = (unsigned short*)ws;                       // 32 MiB
  unsigned short* W2F  = (unsigned short*)(ws + 33554432);          // 256 KiB
  unsigned short* zbf  = (unsigned short*)(ws + 33554432 + 262144); // 64 KiB
  unsigned short* W1F  = (unsigned short*)(ws + 33554432 + 262144 + 65536); // 1 MiB

  prep_all<<<384, 256, 0, stream>>>(z, W1, W2, zbf, W2F, W1F);
  prep_T2<<<dim3(64, 16), 256, 0, stream>>>(zbf, W1F, Tall);
  fused<<<4096, 256, 0, stream>>>(Tall, W2F, zbf, b1, b2, W3, b3, motif, out);
}